// Round 2
// baseline (5140.783 us; speedup 1.0000x reference)
//
#include <hip/hip_runtime.h>

#define BN 64
#define SN 128
#define TN 64
#define FN 100
#define G3 300

__device__ __forceinline__ float rl(float v, int l){
  return __int_as_float(__builtin_amdgcn_readlane(__float_as_int(v), l));
}
__device__ __forceinline__ float fast_exp(float x){        // e^x
  return __builtin_amdgcn_exp2f(x * 1.44269504088896341f);
}
__device__ __forceinline__ float fast_tanh(float x){
  float e = __builtin_amdgcn_exp2f(x * 2.88539008177792681f);
  return 1.0f - 2.0f * __builtin_amdgcn_rcpf(1.0f + e);
}
__device__ __forceinline__ float fast_sig(float x){
  return __builtin_amdgcn_rcpf(1.0f + __builtin_amdgcn_exp2f(-1.44269504088896341f * x));
}

// lgkm-only barrier: no vmcnt drain (the __syncthreads drain was the R1 stall).
#define BARS() asm volatile("s_waitcnt lgkmcnt(0)\n\ts_barrier" ::: "memory")
#define WAIT_VM0() asm volatile("s_waitcnt vmcnt(0)" ::: "memory")

// ---------------------------------------------------------------------------
// Kernel 1: xw[row][o] = sum_f x[row][f]*W[f][o] + b[o], rows = B*S*T = 524288.
// Lane l owns output cols l and 64+l; W in 200 VGPRs (loaded once).
// x broadcast by v_readlane from lane-contiguous register tiles (coalesced).
// 300 VALU instr / row -> ~64 us ideal on the 157 TF vector ALU.
// ---------------------------------------------------------------------------
__global__ __launch_bounds__(512, 2) void k_xw(
    const float* __restrict__ x, const float* __restrict__ W,
    const float* __restrict__ b, float* __restrict__ xw)
{
  const int tid  = threadIdx.x;
  const int lane = tid & 63;
  const int wid  = tid >> 6;
  const long rowBase = ((long)blockIdx.x * 8 + wid) * 256;   // 256 rows per wave

  const bool hasB = (lane < 36);
  float wA[FN], wB[FN];
  #pragma unroll 1
  for (int f = 0; f < FN; f++){
    wA[f] = W[f*FN + lane];
    wB[f] = hasB ? W[f*FN + 64 + lane] : 0.0f;
  }
  const float ba  = b[lane];
  const float bb2 = hasB ? b[64 + lane] : 0.0f;

  const float* xp = x + rowBase * FN;
  float xg[13], xh[13];
  #pragma unroll
  for (int r = 0; r < 13; r++)
    xg[r] = (r*64 + lane < 800) ? xp[r*64 + lane] : 0.0f;

  #pragma unroll 1
  for (int grp = 0; grp < 32; grp++){
    if (grp < 31){                       // prefetch next 8-row tile (coalesced)
      const float* xq = xp + (grp+1)*800;
      #pragma unroll
      for (int r = 0; r < 13; r++)
        xh[r] = (r*64 + lane < 800) ? xq[r*64 + lane] : 0.0f;
    }
    #pragma unroll
    for (int g = 0; g < 8; g++){
      float accA = ba, accB = bb2;
      #pragma unroll
      for (int f = 0; f < FN; f++){
        const int idx = g*FN + f;                 // compile-time after unroll
        float s = rl(xg[idx >> 6], idx & 63);
        accA = fmaf(s, wA[f], accA);
        accB = fmaf(s, wB[f], accB);
      }
      const long row = rowBase + grp*8 + g;
      xw[row*FN + lane] = accA;
      if (hasB) xw[row*FN + 64 + lane] = accB;
    }
    #pragma unroll
    for (int r = 0; r < 13; r++) xg[r] = xh[r];
  }
}

// ---------------------------------------------------------------------------
// Kernel 2: per-batch sequential scan. One block (512 thr, 8 waves) per batch.
// Raw lgkm barriers; single vmcnt(0) per step placed where all outstanding
// global ops are already old; prefetches issued right after phase B.
// ---------------------------------------------------------------------------
__global__ __launch_bounds__(512, 2) void k_scan(
    const float* __restrict__ x, const float* __restrict__ xw,
    const float* __restrict__ Wc, const float* __restrict__ u,
    const float* __restrict__ Wx, const float* __restrict__ Wh,
    const float* __restrict__ bg, float* __restrict__ out)
{
  const int b    = blockIdx.x;
  const int tid  = threadIdx.x;
  const int lane = tid & 63;
  const int wid  = tid >> 6;

  const int gth = tid & 127;      // phase A/D: 4 f-slices of 25 x 128 outputs
  const int fsl = tid >> 7;
  const int tB  = tid >> 3;       // phase B: 64 t x 8 f-slices of 14
  const int fsB = tid & 7;
  const bool fCv = (tid & 127) < FN;   // phase C: f x 4 t-slices of 16
  const int fC  = fCv ? (tid & 127) : (FN - 1);
  const int tsC = tid >> 7;

  __shared__ __align__(16) float xwbuf[2][TN*FN + 16];
  __shared__ float part5[700][5];
  __shared__ float h_lds[128];
  __shared__ __align__(16) float c_lds[128];
  __shared__ float att_lds[128];
  __shared__ __align__(16) float ea_lds[64];
  __shared__ float dpart[8];

  float wr[25][5];
  float wcr[25];
  const bool hasC = (gth >= 28);
  const int  co   = hasC ? gth - 28 : 0;
  #pragma unroll
  for (int j = 0; j < 25; j++){
    const int f = fsl*25 + j;
    #pragma unroll
    for (int p = 0; p < 5; p++){
      const int o = gth + 128*p;
      wr[j][p] = (o < 600) ? ((o < 300) ? Wx[f*G3 + o] : Wh[f*G3 + (o-300)]) : 0.0f;
    }
    wcr[j] = hasC ? Wc[f*FN + co] : 0.0f;
  }
  float2 ur[7];
  #pragma unroll
  for (int i = 0; i < 7; i++){
    const int f = fsB*14 + 2*i;
    ur[i].x = (f   < FN) ? u[f]   : 0.0f;
    ur[i].y = (f+1 < FN) ? u[f+1] : 0.0f;
  }
  // hoisted loop-invariant biases for the GRU phase
  const int gg = (tid < FN) ? tid : 0;
  const float bgz = bg[gg], bgr = bg[FN+gg], bgh = bg[2*FN+gg];

  if (tid < 128){ h_lds[tid] = 0.0f; c_lds[tid] = 0.0f; att_lds[tid] = 0.0f; }
  if (tid < 16){ xwbuf[0][TN*FN + tid] = 0.0f; xwbuf[1][TN*FN + tid] = 0.0f; }
  __syncthreads();   // one-time init barrier (full drain ok here)

  const long tileStride = (long)TN*FN;                 // 6400
  const float* xw_base = xw + (long)b*SN*tileStride;
  const float* x_base  = x  + (long)b*SN*tileStride;

  auto issue_xw_dma = [&](int s, int bi){
    const char* g = (const char*)(xw_base + (long)s*tileStride);
    char* l = (char*)(&xwbuf[bi][0]);
    #pragma unroll
    for (int r = 0; r < 4; r++){
      const int chunk = (r*8 + wid) * 1024;
      if (chunk < 25600){
        __builtin_amdgcn_global_load_lds(
          (const __attribute__((address_space(1))) unsigned int*)(g + chunk + lane*16),
          (__attribute__((address_space(3))) unsigned int*)(l + chunk),
          16, 0, 0);
      }
    }
  };

#define ISSUE_X(sp, arr) do { \
    const float* gp_ = x_base + (long)(sp)*tileStride + (long)tsC*(16*FN) + fC; \
    _Pragma("unroll") \
    for (int k_ = 0; k_ < 16; k_++) arr[k_] = gp_[k_*FN]; \
  } while(0)

  float xcur[16], xnxt[16];
  issue_xw_dma(0, 0);
  ISSUE_X(0, xcur);

  for (int s = 0; s < SN; s++){
    // ---- phase A: c = h @ Wc ----
    float hp = h_lds[fsl*25 + (lane < 25 ? lane : 0)];
    float accC = 0.0f;
    #pragma unroll
    for (int j = 0; j < 25; j++) accC = fmaf(rl(hp, j), wcr[j], accC);
    if (hasC) part5[600 + co][fsl] = accC;
    BARS();                                             // bar1

    if (tid < FN)
      c_lds[tid] = part5[600+tid][0] + part5[600+tid][1]
                 + part5[600+tid][2] + part5[600+tid][3];
    // Drain point: DMA issued last iter (long landed), out-stores from last
    // GRU (~600 cy old). Before the barrier -> cross-wave LDS-DMA safety.
    WAIT_VM0();
    BARS();                                             // bar2

    // ---- phase B: ait[t] = sum_f u[f]*tanh(xw + c), ea = exp(ait) ----
    {
      const float2* cp  = reinterpret_cast<const float2*>(&c_lds[fsB*14]);
      const float2* xp2 = reinterpret_cast<const float2*>(&xwbuf[s&1][tB*FN + fsB*14]);
      float accB = 0.0f;
      #pragma unroll
      for (int i = 0; i < 7; i++){
        float2 cc = cp[i];
        float2 xx = xp2[i];
        accB = fmaf(fast_tanh(xx.x + cc.x), ur[i].x, accB);
        accB = fmaf(fast_tanh(xx.y + cc.y), ur[i].y, accB);
      }
      accB += __shfl_xor(accB, 1);
      accB += __shfl_xor(accB, 2);
      accB += __shfl_xor(accB, 4);
      float ea = fast_exp(accB);
      if (fsB == 0) ea_lds[tB] = ea;
      float dsum = ea;
      dsum += __shfl_xor(dsum, 8);
      dsum += __shfl_xor(dsum, 16);
      dsum += __shfl_xor(dsum, 32);
      if (lane == 0) dpart[wid] = dsum;
    }
    BARS();                                             // bar3

    // ---- issue prefetches for s+1 (consumed >2000 cy from now) ----
    {
      const int sp = (s+1 < SN) ? s+1 : s;
      issue_xw_dma(sp, (s+1)&1);
      ISSUE_X(sp, xnxt);
    }

    // ---- phase C: attended partials (unnormalized) ----
    {
      const float4* eap = reinterpret_cast<const float4*>(&ea_lds[tsC*16]);
      float4 e0 = eap[0], e1 = eap[1], e2 = eap[2], e3 = eap[3];
      float a = 0.0f;
      a = fmaf(xcur[0],  e0.x, a); a = fmaf(xcur[1],  e0.y, a);
      a = fmaf(xcur[2],  e0.z, a); a = fmaf(xcur[3],  e0.w, a);
      a = fmaf(xcur[4],  e1.x, a); a = fmaf(xcur[5],  e1.y, a);
      a = fmaf(xcur[6],  e1.z, a); a = fmaf(xcur[7],  e1.w, a);
      a = fmaf(xcur[8],  e2.x, a); a = fmaf(xcur[9],  e2.y, a);
      a = fmaf(xcur[10], e2.z, a); a = fmaf(xcur[11], e2.w, a);
      a = fmaf(xcur[12], e3.x, a); a = fmaf(xcur[13], e3.y, a);
      a = fmaf(xcur[14], e3.z, a); a = fmaf(xcur[15], e3.w, a);
      if (fCv) part5[600 + fC][tsC] = a;
    }
    BARS();                                             // bar4

    if (tid < FN){
      float den = dpart[0]+dpart[1]+dpart[2]+dpart[3]
                + dpart[4]+dpart[5]+dpart[6]+dpart[7] + 1e-7f;
      float sm = part5[600+tid][0]+part5[600+tid][1]
               + part5[600+tid][2]+part5[600+tid][3];
      att_lds[tid] = sm / den;
    }
    BARS();                                             // bar5

    // ---- phase D: gx = att@Wx, gh = h@Wh ----
    {
      float attp = att_lds[fsl*25 + (lane < 25 ? lane : 0)];
      const bool p2x = (gth < 44);
      float a0=0.f, a1=0.f, a2=0.f, a3=0.f, a4=0.f;
      #pragma unroll
      for (int j = 0; j < 25; j++){
        float sa = rl(attp, j);
        float sh = rl(hp, j);
        float s2 = p2x ? sa : sh;
        a0 = fmaf(sa, wr[j][0], a0);
        a1 = fmaf(sa, wr[j][1], a1);
        a2 = fmaf(s2, wr[j][2], a2);
        a3 = fmaf(sh, wr[j][3], a3);
        a4 = fmaf(sh, wr[j][4], a4);
      }
      part5[gth      ][fsl] = a0;
      part5[gth + 128][fsl] = a1;
      part5[gth + 256][fsl] = a2;
      part5[gth + 384][fsl] = a3;
      if (gth < 88) part5[gth + 512][fsl] = a4;
    }
    BARS();                                             // bar6

    // ---- GRU update ----
    if (tid < FN){
      const int g = tid;
      float gxz = part5[g    ][0]+part5[g    ][1]+part5[g    ][2]+part5[g    ][3] + bgz;
      float gxr = part5[100+g][0]+part5[100+g][1]+part5[100+g][2]+part5[100+g][3] + bgr;
      float gxh = part5[200+g][0]+part5[200+g][1]+part5[200+g][2]+part5[200+g][3] + bgh;
      float ghz = part5[300+g][0]+part5[300+g][1]+part5[300+g][2]+part5[300+g][3];
      float ghr = part5[400+g][0]+part5[400+g][1]+part5[400+g][2]+part5[400+g][3];
      float ghh = part5[500+g][0]+part5[500+g][1]+part5[500+g][2]+part5[500+g][3];
      float z  = fast_sig(gxz + ghz);
      float r  = fast_sig(gxr + ghr);
      float ht = fast_tanh(gxh + r*ghh);
      float hn = (1.0f - z)*h_lds[g] + z*ht;
      h_lds[g] = hn;
      out[((long)b*SN + s)*FN + g] = hn;
    }
    BARS();                                             // bar7
    #pragma unroll
    for (int k = 0; k < 16; k++) xcur[k] = xnxt[k];
  }
#undef ISSUE_X
}

extern "C" void kernel_launch(void* const* d_in, const int* in_sizes, int n_in,
                              void* d_out, int out_size, void* d_ws, size_t ws_size,
                              hipStream_t stream)
{
  const float* x  = (const float*)d_in[0];
  const float* W  = (const float*)d_in[1];
  const float* Wc = (const float*)d_in[2];
  const float* bb = (const float*)d_in[3];
  const float* u  = (const float*)d_in[4];
  const float* Wx = (const float*)d_in[5];
  const float* Wh = (const float*)d_in[6];
  const float* bg = (const float*)d_in[7];
  float* out = (float*)d_out;
  float* xwbuf = (float*)d_ws;   // B*S*T*F*4 = 209,715,200 bytes

  k_xw  <<<dim3(256), dim3(512), 0, stream>>>(x, W, bb, xwbuf);
  k_scan<<<dim3(BN), dim3(512), 0, stream>>>(x, xwbuf, Wc, u, Wx, Wh, bg, out);
}

// Round 3
// 954.237 us; speedup vs baseline: 5.3873x; 5.3873x over previous
//
#include <hip/hip_runtime.h>

#define BN 64
#define SN 128
#define TN 64
#define FN 100
#define G3 300

__device__ __forceinline__ float rl(float v, int l){
  return __int_as_float(__builtin_amdgcn_readlane(__float_as_int(v), l));
}
__device__ __forceinline__ float fast_exp(float x){        // e^x
  return __builtin_amdgcn_exp2f(x * 1.44269504088896341f);
}
__device__ __forceinline__ float fast_tanh(float x){
  float e = __builtin_amdgcn_exp2f(x * 2.88539008177792681f);
  return 1.0f - 2.0f * __builtin_amdgcn_rcpf(1.0f + e);
}
__device__ __forceinline__ float fast_sig(float x){
  return __builtin_amdgcn_rcpf(1.0f + __builtin_amdgcn_exp2f(-1.44269504088896341f * x));
}

#define BARS() asm volatile("s_waitcnt lgkmcnt(0)\n\ts_barrier" ::: "memory")
#define WAIT_VM0() asm volatile("s_waitcnt vmcnt(0)" ::: "memory")

// ---------------------------------------------------------------------------
// Kernel 1: xw = x @ W + b.  Block = 256 thr = 64 rows; wave c owns cols
// [25c, 25c+25). Lane owns a row. W/b indices are wave-uniform (readfirstlane)
// -> scalar loads (s_load, scalar cache), zero VALU cost. x via LDS pad-101.
// Per-thread regs ~45: no spill by construction.
// ---------------------------------------------------------------------------
__global__ __launch_bounds__(256) void k_xw(
    const float* __restrict__ x, const float* __restrict__ W,
    const float* __restrict__ b, float* __restrict__ xw)
{
  const int tid  = threadIdx.x;
  const int lane = tid & 63;
  const int c    = __builtin_amdgcn_readfirstlane(tid >> 6);   // 0..3, uniform
  const int c25  = c * 25;

  __shared__ float xs[64 * 101];
  const long rowbase = (long)blockIdx.x * 64;
  const float* xsrc = x + rowbase * FN;
  #pragma unroll
  for (int i = 0; i < 25; i++){
    const int o = i * 256 + tid;          // coalesced
    const int r = o / FN;
    const int k = o - r * FN;
    xs[r * 101 + k] = xsrc[o];
  }
  __syncthreads();

  float acc[25];
  const float* bp = b + c25;
  #pragma unroll
  for (int j = 0; j < 25; j++) acc[j] = bp[j];      // uniform -> s_load

  const float* Wp = W + c25;
  #pragma unroll 4
  for (int k = 0; k < FN; k++){
    const float xv = xs[lane * 101 + k];            // conflict-free ds_read
    const float* Wk = Wp + (long)k * FN;            // uniform -> s_load row
    #pragma unroll
    for (int j = 0; j < 25; j++) acc[j] = fmaf(xv, Wk[j], acc[j]);
  }

  float* op = xw + (rowbase + lane) * FN + c25;
  #pragma unroll
  for (int j = 0; j < 25; j++) op[j] = acc[j];
}

// ---------------------------------------------------------------------------
// Kernel 2: per-batch scan. 512 thr (8 waves) per batch.
// waves_per_eu(2,2): register budget 256 -> wr[25][5] stays in VGPRs.
// x AND xw tiles staged by global_load_lds DMA (double-buffered).
// ---------------------------------------------------------------------------
__global__
__attribute__((amdgpu_flat_work_group_size(512, 512)))
__attribute__((amdgpu_waves_per_eu(2, 2)))
void k_scan(
    const float* __restrict__ x, const float* __restrict__ xw,
    const float* __restrict__ Wc, const float* __restrict__ u,
    const float* __restrict__ Wx, const float* __restrict__ Wh,
    const float* __restrict__ bg, float* __restrict__ out)
{
  const int b    = blockIdx.x;
  const int tid  = threadIdx.x;
  const int lane = tid & 63;
  const int wid  = tid >> 6;

  const int gth = tid & 127;      // phase A/D: 4 f-slices of 25 x 128 outputs
  const int fsl = tid >> 7;
  const int tB  = tid >> 3;       // phase B: 64 t x 8 f-slices of 14
  const int fsB = tid & 7;
  const bool fCv = (tid & 127) < FN;   // phase C: f x 4 t-slices of 16
  const int fC  = fCv ? (tid & 127) : (FN - 1);
  const int tsC = tid >> 7;

  __shared__ __align__(16) float xwbuf[2][TN*FN + 16];  // pad: phase B tail reads f<112
  __shared__ __align__(16) float xbuf[2][TN*FN];
  __shared__ float part5[700][5];
  __shared__ float h_lds[128];
  __shared__ float c_lds[128];
  __shared__ float att_unused[4];                       // keep layout simple
  __shared__ float ea_lds[64];
  __shared__ __align__(16) float dpart[8];

  float wr[25][5];
  float wcr[25];
  const bool hasC = (gth >= 28);
  const int  co   = hasC ? gth - 28 : 0;
  #pragma unroll
  for (int j = 0; j < 25; j++){
    const int f = fsl*25 + j;
    #pragma unroll
    for (int p = 0; p < 5; p++){
      const int o = gth + 128*p;
      wr[j][p] = (o < 600) ? ((o < 300) ? Wx[f*G3 + o] : Wh[f*G3 + (o-300)]) : 0.0f;
    }
    wcr[j] = hasC ? Wc[f*FN + co] : 0.0f;
  }
  float2 ur[7];
  #pragma unroll
  for (int i = 0; i < 7; i++){
    const int f = fsB*14 + 2*i;
    ur[i].x = (f   < FN) ? u[f]   : 0.0f;
    ur[i].y = (f+1 < FN) ? u[f+1] : 0.0f;
  }
  const int gg = (tid < FN) ? tid : 0;
  const float bgz = bg[gg], bgr = bg[FN+gg], bgh = bg[2*FN+gg];

  if (tid < 128){ h_lds[tid] = 0.0f; c_lds[tid] = 0.0f; }
  if (tid < 16){ xwbuf[0][TN*FN + tid] = 0.0f; xwbuf[1][TN*FN + tid] = 0.0f; }
  __syncthreads();   // one-time init

  const long tileStride = (long)TN*FN;                 // 6400 floats = 25600 B
  const float* xw_base = xw + (long)b*SN*tileStride;
  const float* x_base  = x  + (long)b*SN*tileStride;

  auto issue_tile = [&](const float* gsrc, float* ldst){
    const char* g = (const char*)gsrc;
    char* l = (char*)ldst;
    #pragma unroll
    for (int r = 0; r < 4; r++){
      const int chunk = (r*8 + wid) * 1024;
      if (chunk < 25600){
        __builtin_amdgcn_global_load_lds(
          (const __attribute__((address_space(1))) unsigned int*)(g + chunk + lane*16),
          (__attribute__((address_space(3))) unsigned int*)(l + chunk),
          16, 0, 0);
      }
    }
  };

  issue_tile(xw_base, &xwbuf[0][0]);
  issue_tile(x_base,  &xbuf[0][0]);

  for (int s = 0; s < SN; s++){
    // ---- phase A: c = h @ Wc ----
    float hp = h_lds[fsl*25 + (lane < 25 ? lane : 0)];
    float accC = 0.0f;
    #pragma unroll
    for (int j = 0; j < 25; j++) accC = fmaf(rl(hp, j), wcr[j], accC);
    if (hasC) part5[600 + co][fsl] = accC;
    BARS();                                             // bar1

    if (tid < FN)
      c_lds[tid] = part5[600+tid][0] + part5[600+tid][1]
                 + part5[600+tid][2] + part5[600+tid][3];
    // All outstanding DMA was issued >1 full step ago -> cheap drain here,
    // before the barrier (cross-wave safety for the LDS tiles).
    WAIT_VM0();
    BARS();                                             // bar2

    // ---- phase B: ait[t] = sum_f u[f]*tanh(xw + c), ea = exp(ait) ----
    {
      const float2* cp  = reinterpret_cast<const float2*>(&c_lds[fsB*14]);
      const float2* xp2 = reinterpret_cast<const float2*>(&xwbuf[s&1][tB*FN + fsB*14]);
      float accB = 0.0f;
      #pragma unroll
      for (int i = 0; i < 7; i++){
        float2 cc = cp[i];
        float2 xx = xp2[i];
        accB = fmaf(fast_tanh(xx.x + cc.x), ur[i].x, accB);
        accB = fmaf(fast_tanh(xx.y + cc.y), ur[i].y, accB);
      }
      accB += __shfl_xor(accB, 1);
      accB += __shfl_xor(accB, 2);
      accB += __shfl_xor(accB, 4);
      float ea = fast_exp(accB);
      if (fsB == 0) ea_lds[tB] = ea;
      float dsum = ea;
      dsum += __shfl_xor(dsum, 8);
      dsum += __shfl_xor(dsum, 16);
      dsum += __shfl_xor(dsum, 32);
      if (lane == 0) dpart[wid] = dsum;
    }
    BARS();                                             // bar3

    // ---- issue DMA for s+1 (consumed next iter, after WAIT_VM0@bar2) ----
    {
      const int sp = (s+1 < SN) ? s+1 : s;
      issue_tile(xw_base + (long)sp*tileStride, &xwbuf[(s+1)&1][0]);
      issue_tile(x_base  + (long)sp*tileStride, &xbuf[(s+1)&1][0]);
    }

    // ---- phase C: attended partials (unnormalized) ----
    {
      const float* xt = &xbuf[s&1][(long)tsC*(16*FN) + fC];
      const float4* eap = reinterpret_cast<const float4*>(&ea_lds[tsC*16]);
      float4 e0 = eap[0], e1 = eap[1], e2 = eap[2], e3 = eap[3];
      float a = 0.0f;
      a = fmaf(xt[0*FN],  e0.x, a); a = fmaf(xt[1*FN],  e0.y, a);
      a = fmaf(xt[2*FN],  e0.z, a); a = fmaf(xt[3*FN],  e0.w, a);
      a = fmaf(xt[4*FN],  e1.x, a); a = fmaf(xt[5*FN],  e1.y, a);
      a = fmaf(xt[6*FN],  e1.z, a); a = fmaf(xt[7*FN],  e1.w, a);
      a = fmaf(xt[8*FN],  e2.x, a); a = fmaf(xt[9*FN],  e2.y, a);
      a = fmaf(xt[10*FN], e2.z, a); a = fmaf(xt[11*FN], e2.w, a);
      a = fmaf(xt[12*FN], e3.x, a); a = fmaf(xt[13*FN], e3.y, a);
      a = fmaf(xt[14*FN], e3.z, a); a = fmaf(xt[15*FN], e3.w, a);
      if (fCv) part5[600 + fC][tsC] = a;
    }
    BARS();                                             // bar4

    // ---- phase D: att normalize inline, then gx = att@Wx, gh = h@Wh ----
    {
      const float4* dp4 = reinterpret_cast<const float4*>(dpart);
      float4 d0 = dp4[0], d1 = dp4[1];
      float den = d0.x+d0.y+d0.z+d0.w + d1.x+d1.y+d1.z+d1.w + 1e-7f;
      float rden = 1.0f / den;
      const int fA = fsl*25 + (lane < 25 ? lane : 0);
      float attp = (part5[600+fA][0] + part5[600+fA][1]
                  + part5[600+fA][2] + part5[600+fA][3]) * rden;
      const bool p2x = (gth < 44);
      float a0=0.f, a1=0.f, a2=0.f, a3=0.f, a4=0.f;
      #pragma unroll
      for (int j = 0; j < 25; j++){
        float sa = rl(attp, j);
        float sh = rl(hp, j);
        float s2 = p2x ? sa : sh;
        a0 = fmaf(sa, wr[j][0], a0);
        a1 = fmaf(sa, wr[j][1], a1);
        a2 = fmaf(s2, wr[j][2], a2);
        a3 = fmaf(sh, wr[j][3], a3);
        a4 = fmaf(sh, wr[j][4], a4);
      }
      part5[gth      ][fsl] = a0;
      part5[gth + 128][fsl] = a1;
      part5[gth + 256][fsl] = a2;
      part5[gth + 384][fsl] = a3;
      if (gth < 88) part5[gth + 512][fsl] = a4;
    }
    BARS();                                             // bar5

    // ---- GRU update ----
    if (tid < FN){
      const int g = tid;
      float gxz = part5[g    ][0]+part5[g    ][1]+part5[g    ][2]+part5[g    ][3] + bgz;
      float gxr = part5[100+g][0]+part5[100+g][1]+part5[100+g][2]+part5[100+g][3] + bgr;
      float gxh = part5[200+g][0]+part5[200+g][1]+part5[200+g][2]+part5[200+g][3] + bgh;
      float ghz = part5[300+g][0]+part5[300+g][1]+part5[300+g][2]+part5[300+g][3];
      float ghr = part5[400+g][0]+part5[400+g][1]+part5[400+g][2]+part5[400+g][3];
      float ghh = part5[500+g][0]+part5[500+g][1]+part5[500+g][2]+part5[500+g][3];
      float z  = fast_sig(gxz + ghz);
      float r  = fast_sig(gxr + ghr);
      float ht = fast_tanh(gxh + r*ghh);
      float hn = (1.0f - z)*h_lds[g] + z*ht;
      h_lds[g] = hn;
      out[((long)b*SN + s)*FN + g] = hn;
    }
    BARS();                                             // bar6
  }
}

extern "C" void kernel_launch(void* const* d_in, const int* in_sizes, int n_in,
                              void* d_out, int out_size, void* d_ws, size_t ws_size,
                              hipStream_t stream)
{
  const float* x  = (const float*)d_in[0];
  const float* W  = (const float*)d_in[1];
  const float* Wc = (const float*)d_in[2];
  const float* bb = (const float*)d_in[3];
  const float* u  = (const float*)d_in[4];
  const float* Wx = (const float*)d_in[5];
  const float* Wh = (const float*)d_in[6];
  const float* bg = (const float*)d_in[7];
  float* out = (float*)d_out;
  float* xwbuf = (float*)d_ws;   // B*S*T*F*4 = 209,715,200 bytes

  k_xw  <<<dim3((BN*SN*TN)/64), dim3(256), 0, stream>>>(x, W, bb, xwbuf);
  k_scan<<<dim3(BN), dim3(512), 0, stream>>>(x, xwbuf, Wc, u, Wx, Wh, bg, out);
}